// Round 7
// baseline (45.400 us; speedup 1.0000x reference)
//
#include <hip/hip_runtime.h>

// Output: K (8192, 8192) f32 = 256 MB. Pure write-stream bound.
// Persistent-block (fill-like) shape: 2048 blocks x 256 threads resident for
// the whole kernel; each block owns 4 contiguous output rows (128 KB) and
// grid-strides within them. Row-dependent values (X[i], parity d1) are
// block-uniform -> scalar regs. 8 independent plain float4 stores in flight
// per wave per row.

typedef float v4f __attribute__((ext_vector_type(4)));

__global__ void __launch_bounds__(256) rbf_divfree_kernel(
    const float* __restrict__ X,        // (n, 2)
    const float* __restrict__ Y,        // (m, 2)
    const float* __restrict__ lls,      // (1,)
    float* __restrict__ out,            // (2n, 2m) row-major
    int mp,                             // m/2 = float4 cols per row (2048)
    int rows_per_block)                 // 4
{
    const int tid = threadIdx.x;
    const float inv_ls = __expf(-lls[0]);        // 1/ls
    const size_t ldc = (size_t)mp * 4;           // floats per row
    const int row0 = blockIdx.x * rows_per_block;

    for (int r = 0; r < rows_per_block; ++r) {
        const int row = row0 + r;                // block-uniform
        const int i  = row >> 1;
        const int d1 = row & 1;
        const float xi0 = X[2 * i];              // scalar loads
        const float xi1 = X[2 * i + 1];
        float* prow = out + (size_t)row * ldc;

        #pragma unroll
        for (int k = 0; k < 8; ++k) {            // mp / blockDim = 8
            const int jp = tid + (k << 8);
            const v4f y = *reinterpret_cast<const v4f*>(Y + 4 * (size_t)jp);
            v4f rv;
            {   // j = 2*jp
                const float dx = xi0 - y[0];
                const float dy = xi1 - y[1];
                const float t  = (dx * dx + dy * dy) * inv_ls;
                const float ke = __expf(-0.5f * t);
                const float c  = 1.0f - t;
                const float a  = d1 ? dy : dx;
                rv[0] = (dx * a * inv_ls + (d1 ? 0.0f : c)) * ke;
                rv[1] = (dy * a * inv_ls + (d1 ? c : 0.0f)) * ke;
            }
            {   // j = 2*jp+1
                const float dx = xi0 - y[2];
                const float dy = xi1 - y[3];
                const float t  = (dx * dx + dy * dy) * inv_ls;
                const float ke = __expf(-0.5f * t);
                const float c  = 1.0f - t;
                const float a  = d1 ? dy : dx;
                rv[2] = (dx * a * inv_ls + (d1 ? 0.0f : c)) * ke;
                rv[3] = (dy * a * inv_ls + (d1 ? c : 0.0f)) * ke;
            }
            *reinterpret_cast<v4f*>(prow + 4 * (size_t)jp) = rv;
        }
    }
}

extern "C" void kernel_launch(void* const* d_in, const int* in_sizes, int n_in,
                              void* d_out, int out_size, void* d_ws, size_t ws_size,
                              hipStream_t stream) {
    const float* X   = (const float*)d_in[0];
    const float* Y   = (const float*)d_in[1];
    const float* lls = (const float*)d_in[2];
    float* out = (float*)d_out;

    const int n  = in_sizes[0] / 2;   // 4096
    const int m  = in_sizes[1] / 2;   // 4096
    const int mp = m / 2;             // 2048 float4 columns

    const int nrows = 2 * n;          // 8192 output rows
    const int blocks = 2048;          // 8 per CU
    const int rpb = nrows / blocks;   // 4 rows per block

    rbf_divfree_kernel<<<blocks, 256, 0, stream>>>(X, Y, lls, out, mp, rpb);
}

// Round 8
// 43.816 us; speedup vs baseline: 1.0362x; 1.0362x over previous
//
#include <hip/hip_runtime.h>

// Output: K (8192, 8192) f32 = 256 MB. Pure write-stream bound.
// R6 shape (1024-thread blocks, plain float4 stores) but each thread now
// emits the full 2x4 patch for its (i, jp): two stores ldc apart.
// Halves exp/Y-load/index work per byte. grid (2, 4096) = 8192 blocks.

typedef float v4f __attribute__((ext_vector_type(4)));

__global__ void __launch_bounds__(1024) rbf_divfree_kernel(
    const float* __restrict__ X,        // (n, 2)
    const float* __restrict__ Y,        // (m, 2)
    const float* __restrict__ lls,      // (1,)
    float* __restrict__ out,            // (2n, 2m) row-major
    int mp)                             // mp = m/2 = float4 cols per row
{
    const int jp = blockIdx.x * blockDim.x + threadIdx.x;  // float4 col
    const int i  = blockIdx.y;                             // row pair index

    const float inv_ls = __expf(-lls[0]);        // 1/ls
    const size_t ldc = (size_t)mp * 4;           // floats per output row

    const float xi0 = X[2 * i];
    const float xi1 = X[2 * i + 1];
    const v4f y = *reinterpret_cast<const v4f*>(Y + 4 * (size_t)jp);

    v4f r0, r1;
    {   // j = 2*jp  (y[0], y[1])
        const float dx = xi0 - y[0];
        const float dy = xi1 - y[1];
        const float t  = (dx * dx + dy * dy) * inv_ls;   // dist/ls
        const float ke = __expf(-0.5f * t);              // SIGMA_VAR = 1
        const float c  = 1.0f - t;                       // (d-1) - dist/ls
        r0[0] = (dx * dx * inv_ls + c) * ke;             // A00
        r0[1] = (dx * dy * inv_ls) * ke;                 // A01
        r1[0] = r0[1];                                   // A10
        r1[1] = (dy * dy * inv_ls + c) * ke;             // A11
    }
    {   // j = 2*jp+1  (y[2], y[3])
        const float dx = xi0 - y[2];
        const float dy = xi1 - y[3];
        const float t  = (dx * dx + dy * dy) * inv_ls;
        const float ke = __expf(-0.5f * t);
        const float c  = 1.0f - t;
        r0[2] = (dx * dx * inv_ls + c) * ke;
        r0[3] = (dx * dy * inv_ls) * ke;
        r1[2] = r0[3];
        r1[3] = (dy * dy * inv_ls + c) * ke;
    }

    float* p0 = out + (size_t)(2 * i) * ldc + 4 * (size_t)jp;
    *reinterpret_cast<v4f*>(p0)       = r0;   // row 2i
    *reinterpret_cast<v4f*>(p0 + ldc) = r1;   // row 2i+1
}

extern "C" void kernel_launch(void* const* d_in, const int* in_sizes, int n_in,
                              void* d_out, int out_size, void* d_ws, size_t ws_size,
                              hipStream_t stream) {
    const float* X   = (const float*)d_in[0];
    const float* Y   = (const float*)d_in[1];
    const float* lls = (const float*)d_in[2];
    float* out = (float*)d_out;

    const int n  = in_sizes[0] / 2;   // 4096
    const int m  = in_sizes[1] / 2;   // 4096
    const int mp = m / 2;             // 2048 float4 columns

    const int block = 1024;
    dim3 grid(mp / block, n);         // (2, 4096) = 8192 blocks

    rbf_divfree_kernel<<<grid, block, 0, stream>>>(X, Y, lls, out, mp);
}